// Round 3
// baseline (132.248 us; speedup 1.0000x reference)
//
#include <hip/hip_runtime.h>

#define B_  2
#define T_  2048
#define D_  512
#define H_  8
#define HD_ 64
#define WHALF_ 16
#define Mtot (B_*T_)

typedef __attribute__((ext_vector_type(8))) short short8;   // 8 bf16 in 4 VGPRs
typedef __attribute__((ext_vector_type(4))) short short4v;
typedef __attribute__((ext_vector_type(4))) float floatx4;  // MFMA accumulator

__device__ __forceinline__ unsigned short f2bf(float f) {
    unsigned u = __float_as_uint(f);
    u = (u + 0x7fffu + ((u >> 16) & 1u)) >> 16;   // RNE
    return (unsigned short)u;
}

__device__ __forceinline__ void glds16(const unsigned short* g, unsigned short* l) {
    // async global->LDS, 16 B/lane; LDS dest = wave-uniform base + lane*16
    __builtin_amdgcn_global_load_lds(
        (const __attribute__((address_space(1))) void*)g,
        (__attribute__((address_space(3))) void*)l, 16, 0, 0);
}

// ---------------------------------------------------------------------------
// Fused cast kernel. Also zeroes the 2 KB OOB-row scratch (zb).
// ---------------------------------------------------------------------------
__global__ __launch_bounds__(256) void cast_all(
    const float* __restrict__ x,
    const float* __restrict__ Wq, const float* __restrict__ Wk,
    const float* __restrict__ Wv, const float* __restrict__ Wo,
    const float* __restrict__ bq, const float* __restrict__ bk,
    const float* __restrict__ bv,
    unsigned short* __restrict__ xb,
    unsigned short* __restrict__ wqkv, unsigned short* __restrict__ wob,
    float* __restrict__ bqkv, unsigned short* __restrict__ zb)
{
    if (blockIdx.x < 2048) {
        int i = blockIdx.x * 256 + threadIdx.x;
        float4 f = ((const float4*)x)[i];
        ushort4 o;
        o.x = f2bf(f.x); o.y = f2bf(f.y); o.z = f2bf(f.z); o.w = f2bf(f.w);
        ((ushort4*)xb)[i] = o;
    } else if (blockIdx.x < 3072) {
        int gid = (blockIdx.x - 2048) * 256 + threadIdx.x;
        int m   = gid >> 16;
        int idx = gid & 0xFFFF;
        const float* src = (m == 0) ? Wq : (m == 1) ? Wk : (m == 2) ? Wv : Wo;
        float4 f = ((const float4*)src)[idx];
        ushort4 o;
        o.x = f2bf(f.x); o.y = f2bf(f.y); o.z = f2bf(f.z); o.w = f2bf(f.w);
        if (m < 3) ((ushort4*)wqkv)[(m << 16) + idx] = o;
        else       ((ushort4*)wob)[idx] = o;
    } else {
        for (int i = threadIdx.x; i < 384; i += 256) {
            const float* src = (i < 128) ? bq : (i < 256) ? bk : bv;
            ((float4*)bqkv)[i] = ((const float4*)src)[i & 127];
        }
        // zero 2 KB OOB scratch
        if (threadIdx.x < 128) {
            float4 z; z.x = 0.f; z.y = 0.f; z.z = 0.f; z.w = 0.f;
            ((float4*)zb)[threadIdx.x] = z;
        }
    }
}

// ---------------------------------------------------------------------------
// FUSED QKV-projection + local-window attention, v2.
// Changes vs v1:
//  - W (B-operand) fragments are loaded DIRECTLY global->VGPR. W rows have
//    zero intra-block reuse, so LDS staging of W was a pure pass-through
//    (glds + barrier-drain + ds_read for a single use). W is 1.5 MB and
//    L2/L3-resident. Since the x-tile XOR swizzle cancels on read, the
//    global column offset is plain k0+ks*32+quad*8 (uniform, offset-folded).
//  - Only the x tile (2-3x intra-block reuse) stays in LDS, now DOUBLE-
//    buffered with stage-before-compute (T3-minimum 2-phase): one barrier
//    per K-step instead of two; staged bytes per K-step 18KB -> 3KB.
// LDS: x dbuf 24 KB + Qs/Ks/Vs 37.6 KB ~= 61 KB -> 2 blocks/CU.
// ---------------------------------------------------------------------------
#define QLD 72
#define VLD 76

__global__ __launch_bounds__(256) void qkv_attn(
    const unsigned short* __restrict__ xb,
    const unsigned short* __restrict__ wqkv,
    const float* __restrict__ bqkv,
    const unsigned short* __restrict__ zb,
    unsigned short* __restrict__ att)
{
    // S: double-buffered x staging. Each buffer: 96 rows (q0-16..q0+79) x 64.
    __shared__ unsigned short S[2 * 96 * 64];     // 24 KB, reused as Pws later
    __shared__ unsigned short Qs[64][QLD];
    __shared__ unsigned short Ks[96][QLD];
    __shared__ unsigned short Vs[96][VLD];

    const int q0 = blockIdx.x * 64;
    const int bh = blockIdx.y;
    const int b = bh >> 3, h = bh & 7;
    const int t = threadIdx.x;
    const int w = t >> 6, l = t & 63;
    const int quad = l >> 4, lo = l & 15;
    const int lr  = l >> 3;
    const int csw = ((l & 7) ^ lr) * 8;      // swizzled source col offset

    // ---- x staging pointers: 3 chunks/wave, 8 rows x 64 cols each ----
    const unsigned short* src[3];
    #pragma unroll
    for (int i = 0; i < 3; ++i) {
        int c = w * 3 + i;                     // chunk 0..11
        int g0 = q0 - 16 + 8 * c;              // chunks fully in or fully out
        src[i] = (g0 >= 0 && g0 < T_)
               ? (xb + (size_t)(b * T_ + g0 + lr) * 512 + csw)
               : (zb + csw);                   // zeros; +k0<=448 stays in 2 KB
    }

    // ---- W fragment base pointers (direct global, per-lane row) ----
    // wave0: Wq, wave1: Wk, wave2: Wv, wave3: Wk (Bb) + Wv (Bb2)
    const int mw = (w == 3) ? 1 : w;
    const unsigned short* Bb[4];
    const unsigned short* Bb2[4];
    #pragma unroll
    for (int n = 0; n < 4; ++n) {
        Bb[n]  = wqkv + (size_t)mw * 262144 + (size_t)(h * 64 + n * 16 + lo) * 512 + quad * 8;
        Bb2[n] = wqkv + (size_t)2  * 262144 + (size_t)(h * 64 + n * 16 + lo) * 512 + quad * 8;
    }

    floatx4 acc[4][4];
    #pragma unroll
    for (int m = 0; m < 4; ++m)
        #pragma unroll
        for (int n = 0; n < 4; ++n) acc[m][n] = (floatx4)0.0f;

    const int swlo = lo & 7;

    // ---- prologue: stage k0=0 into buffer 0 ----
    #pragma unroll
    for (int i = 0; i < 3; ++i) glds16(src[i], &S[(w * 3 + i) * 512]);
    __syncthreads();

    // ---- in-block GEMM: K=512, BK=64, 2-phase (stage next || compute cur) ----
    int buf = 0;
    for (int k0 = 0; k0 < 512; k0 += 64) {
        const int nbuf = buf ^ 1;
        if (k0 < 448) {
            #pragma unroll
            for (int i = 0; i < 3; ++i)
                glds16(src[i] + k0 + 64, &S[nbuf * 6144 + (w * 3 + i) * 512]);
        }
        const int base = buf * 6144;

        #pragma unroll
        for (int ks = 0; ks < 2; ++ks) {
            const int cg = ((ks * 4 + quad) ^ swlo) * 8;
            const int gcol = k0 + ks * 32;
            if (w != 3) {
                // wave0: Q (x rows 16..79); wave1: K rows 0..63; wave2: V rows 0..63
                const int ab = (w == 0) ? 16 : 0;
                short8 a[4], bf[4];
                #pragma unroll
                for (int m = 0; m < 4; ++m)
                    a[m] = *(const short8*)(&S[base + (ab + m * 16 + lo) * 64 + cg]);
                #pragma unroll
                for (int n = 0; n < 4; ++n)
                    bf[n] = *(const short8*)(Bb[n] + gcol);
                #pragma unroll
                for (int m = 0; m < 4; ++m)
                    #pragma unroll
                    for (int n = 0; n < 4; ++n)
                        acc[m][n] = __builtin_amdgcn_mfma_f32_16x16x32_bf16(a[m], bf[n], acc[m][n], 0, 0, 0);
            } else {
                // wave3: K rows 64..95 (acc[0..1]) + V rows 64..95 (acc[2..3])
                short8 a2[2], bk4[4], bv4[4];
                #pragma unroll
                for (int j = 0; j < 2; ++j)
                    a2[j] = *(const short8*)(&S[base + (64 + j * 16 + lo) * 64 + cg]);
                #pragma unroll
                for (int n = 0; n < 4; ++n) {
                    bk4[n] = *(const short8*)(Bb[n]  + gcol);
                    bv4[n] = *(const short8*)(Bb2[n] + gcol);
                }
                #pragma unroll
                for (int n = 0; n < 4; ++n) {
                    acc[0][n] = __builtin_amdgcn_mfma_f32_16x16x32_bf16(a2[0], bk4[n], acc[0][n], 0, 0, 0);
                    acc[1][n] = __builtin_amdgcn_mfma_f32_16x16x32_bf16(a2[1], bk4[n], acc[1][n], 0, 0, 0);
                    acc[2][n] = __builtin_amdgcn_mfma_f32_16x16x32_bf16(a2[0], bv4[n], acc[2][n], 0, 0, 0);
                    acc[3][n] = __builtin_amdgcn_mfma_f32_16x16x32_bf16(a2[1], bv4[n], acc[3][n], 0, 0, 0);
                }
            }
        }
        __syncthreads();   // drains this iter's stage; next buffer ready
        buf = nbuf;
    }

    // ---- epilogue: Q/K/V -> attn LDS tiles, bias + f2bf ----
    if (w == 0) {
        #pragma unroll
        for (int n = 0; n < 4; ++n) {
            float bb = bqkv[h * 64 + n * 16 + lo];
            #pragma unroll
            for (int m = 0; m < 4; ++m)
                #pragma unroll
                for (int r = 0; r < 4; ++r)
                    Qs[m * 16 + quad * 4 + r][n * 16 + lo] = f2bf(acc[m][n][r] + bb);
        }
    } else if (w == 1) {
        #pragma unroll
        for (int n = 0; n < 4; ++n) {
            float bb = bqkv[512 + h * 64 + n * 16 + lo];
            #pragma unroll
            for (int m = 0; m < 4; ++m)
                #pragma unroll
                for (int r = 0; r < 4; ++r)
                    Ks[m * 16 + quad * 4 + r][n * 16 + lo] = f2bf(acc[m][n][r] + bb);
        }
    } else if (w == 2) {
        #pragma unroll
        for (int n = 0; n < 4; ++n) {
            float bb = bqkv[1024 + h * 64 + n * 16 + lo];
            #pragma unroll
            for (int m = 0; m < 4; ++m)
                #pragma unroll
                for (int r = 0; r < 4; ++r)
                    Vs[m * 16 + quad * 4 + r][n * 16 + lo] = f2bf(acc[m][n][r] + bb);
        }
    } else {
        #pragma unroll
        for (int n = 0; n < 4; ++n) {
            float bbk = bqkv[512  + h * 64 + n * 16 + lo];
            float bbv = bqkv[1024 + h * 64 + n * 16 + lo];
            #pragma unroll
            for (int j = 0; j < 2; ++j)
                #pragma unroll
                for (int r = 0; r < 4; ++r) {
                    Ks[64 + j * 16 + quad * 4 + r][n * 16 + lo] = f2bf(acc[j][n][r] + bbk);
                    Vs[64 + j * 16 + quad * 4 + r][n * 16 + lo] = f2bf(acc[2 + j][n][r] + bbv);
                }
        }
    }
    __syncthreads();

    // ---- attention phase (proven band-restricted structure) ----
    unsigned short (*Pws)[16][QLD] = (unsigned short (*)[16][QLD])S;  // overlay

    const int wq  = w;
    const int ks0 = wq >> 1;                      // first 32-key chunk
    const int kb  = ks0 * 2;                      // first 16-key tile

    // S = Q K^T over 4 key tiles
    floatx4 Sf[4];
    #pragma unroll
    for (int tt = 0; tt < 4; ++tt) Sf[tt] = (floatx4)0.0f;
    short8 aq[2];
    #pragma unroll
    for (int ks = 0; ks < 2; ++ks)
        aq[ks] = *(const short8*)(&Qs[wq * 16 + lo][ks * 32 + quad * 8]);
    #pragma unroll
    for (int tt = 0; tt < 4; ++tt) {
        #pragma unroll
        for (int ks = 0; ks < 2; ++ks) {
            short8 bk8 = *(const short8*)(&Ks[(kb + tt) * 16 + lo][ks * 32 + quad * 8]);
            Sf[tt] = __builtin_amdgcn_mfma_f32_16x16x32_bf16(aq[ks], bk8, Sf[tt], 0, 0, 0);
        }
    }

    // masked softmax
    float inv_r[4];
    #pragma unroll
    for (int r = 0; r < 4; ++r) {
        int qi = q0 + wq * 16 + quad * 4 + r;
        float mx = -1e30f;
        float sv[4]; bool vd[4];
        #pragma unroll
        for (int tt = 0; tt < 4; ++tt) {
            int j = q0 - WHALF_ + (kb + tt) * 16 + lo;
            bool ok = (j >= qi - WHALF_) && (j < qi + WHALF_) && (j >= 0) && (j < T_);
            float s = Sf[tt][r] * 0.125f;
            sv[tt] = s; vd[tt] = ok;
            mx = (ok && s > mx) ? s : mx;
        }
        #pragma unroll
        for (int mm = 1; mm < 16; mm <<= 1) mx = fmaxf(mx, __shfl_xor(mx, mm, 16));
        float den = 0.f;
        #pragma unroll
        for (int tt = 0; tt < 4; ++tt) {
            float e = vd[tt] ? __expf(sv[tt] - mx) : 0.f;
            Pws[wq][quad * 4 + r][tt * 16 + lo] = f2bf(e);
            den += e;
        }
        #pragma unroll
        for (int mm = 1; mm < 16; mm <<= 1) den += __shfl_xor(den, mm, 16);
        inv_r[r] = 1.0f / den;
    }
    // Pws is wave-private: in-wave lgkmcnt ordering suffices, no barrier.

    // O = P V over 2 key chunks; B-frags gathered from row-major Vs
    floatx4 O[4];
    #pragma unroll
    for (int nt = 0; nt < 4; ++nt) O[nt] = (floatx4)0.0f;
    #pragma unroll
    for (int ksr = 0; ksr < 2; ++ksr) {
        short8 ap = *(const short8*)(&Pws[wq][lo][ksr * 32 + quad * 8]);
        const int krow = (ks0 + ksr) * 32 + quad * 8;
        #pragma unroll
        for (int nt = 0; nt < 4; ++nt) {
            short8 bv8;
            #pragma unroll
            for (int j = 0; j < 8; ++j)
                bv8[j] = (short)Vs[krow + j][nt * 16 + lo];
            O[nt] = __builtin_amdgcn_mfma_f32_16x16x32_bf16(ap, bv8, O[nt], 0, 0, 0);
        }
    }

    // epilogue: scale by 1/den, bf16 out
    #pragma unroll
    for (int r = 0; r < 4; ++r) {
        int qi = q0 + wq * 16 + quad * 4 + r;
        size_t rowb = (size_t)(b * T_ + qi) * D_ + h * HD_;
        #pragma unroll
        for (int nt = 0; nt < 4; ++nt)
            att[rowb + nt * 16 + lo] = f2bf(O[nt][r] * inv_r[r]);
    }
}

// ---------------------------------------------------------------------------
// GEMM2, barrier-free: out[4096,512](f32) = attb(bf16) @ wob^T + bo.
// Reuse is only 2x on A / 2x on B and both operands are L2/L3-resident
// (4.5 MB total), so the LDS round-trip + 16 barriers bought nothing.
// Each wave computes its 32x32 tile with all MFMA fragments loaded directly
// global->VGPR; no LDS, no __syncthreads, full dataflow ILP.
// ---------------------------------------------------------------------------
__global__ __launch_bounds__(256) void gemm_out(
    const unsigned short* __restrict__ attb, const unsigned short* __restrict__ wob,
    const float* __restrict__ bo, float* __restrict__ out)
{
    const int t  = threadIdx.x;
    const int m0 = blockIdx.x * 64;
    const int n0 = blockIdx.y * 64;
    const int w  = t >> 6, l = t & 63;
    const int quad = l >> 4, lo = l & 15;
    const int wr = w >> 1, wc = w & 1;

    const unsigned short* Ab[2];
    const unsigned short* Bb[2];
    #pragma unroll
    for (int m = 0; m < 2; ++m)
        Ab[m] = attb + (size_t)(m0 + wr * 32 + m * 16 + lo) * 512 + quad * 8;
    #pragma unroll
    for (int n = 0; n < 2; ++n)
        Bb[n] = wob + (size_t)(n0 + wc * 32 + n * 16 + lo) * 512 + quad * 8;

    floatx4 acc[2][2];
    #pragma unroll
    for (int m = 0; m < 2; ++m)
        #pragma unroll
        for (int n = 0; n < 2; ++n) acc[m][n] = (floatx4)0.0f;

    #pragma unroll 4
    for (int k0 = 0; k0 < 512; k0 += 32) {
        short8 a[2], bfr[2];
        #pragma unroll
        for (int m = 0; m < 2; ++m) a[m]   = *(const short8*)(Ab[m] + k0);
        #pragma unroll
        for (int n = 0; n < 2; ++n) bfr[n] = *(const short8*)(Bb[n] + k0);
        #pragma unroll
        for (int m = 0; m < 2; ++m)
            #pragma unroll
            for (int n = 0; n < 2; ++n)
                acc[m][n] = __builtin_amdgcn_mfma_f32_16x16x32_bf16(a[m], bfr[n], acc[m][n], 0, 0, 0);
    }

    #pragma unroll
    for (int n = 0; n < 2; ++n) {
        int col = n0 + wc * 32 + n * 16 + lo;
        float bv = bo[col];
        #pragma unroll
        for (int m = 0; m < 2; ++m) {
            #pragma unroll
            for (int r = 0; r < 4; ++r) {
                int row = m0 + wr * 32 + m * 16 + quad * 4 + r;
                out[(size_t)row * 512 + col] = acc[m][n][r] + bv;
            }
        }
    }
}

// ---------------------------------------------------------------------------
extern "C" void kernel_launch(void* const* d_in, const int* in_sizes, int n_in,
                              void* d_out, int out_size, void* d_ws, size_t ws_size,
                              hipStream_t stream) {
    const float* x  = (const float*)d_in[0];
    const float* Wq = (const float*)d_in[1];
    const float* bq = (const float*)d_in[2];
    const float* Wk = (const float*)d_in[3];
    const float* bk = (const float*)d_in[4];
    const float* Wv = (const float*)d_in[5];
    const float* bv = (const float*)d_in[6];
    const float* Wo = (const float*)d_in[7];
    const float* bo = (const float*)d_in[8];
    float* out = (float*)d_out;

    char* ws = (char*)d_ws;
    unsigned short* xb   = (unsigned short*)(ws);                 //  4.00 MB
    unsigned short* wqkv = (unsigned short*)(ws +  4194304);      //  1.50 MB
    unsigned short* wob  = (unsigned short*)(ws +  5767168);      //  0.50 MB
    float*          bqkv = (float*)         (ws +  6291456);      //  6 KB
    unsigned short* zb   = (unsigned short*)(ws +  6297600);      //  2 KB zeros
    unsigned short* attb = (unsigned short*)(ws +  6299648);      //  4.00 MB

    cast_all<<<3073, 256, 0, stream>>>(x, Wq, Wk, Wv, Wo, bq, bk, bv,
                                       xb, wqkv, wob, bqkv, zb);

    // fused QKV projection + local attention: 512 blocks = 2/CU
    qkv_attn<<<dim3(T_ / 64, B_ * H_), 256, 0, stream>>>(
        xb, wqkv, bqkv, zb, attb);

    // output projection, barrier-free: 512 blocks = 2/CU
    gemm_out<<<dim3(Mtot / 64, D_ / 64), 256, 0, stream>>>(attb, wob, bo, out);
}

// Round 4
// 102.090 us; speedup vs baseline: 1.2954x; 1.2954x over previous
//
#include <hip/hip_runtime.h>

#define B_  2
#define T_  2048
#define D_  512
#define H_  8
#define HD_ 64
#define WHALF_ 16
#define Mtot (B_*T_)

typedef __attribute__((ext_vector_type(8))) short short8;   // 8 bf16 in 4 VGPRs
typedef __attribute__((ext_vector_type(4))) short short4v;
typedef __attribute__((ext_vector_type(4))) float floatx4;  // MFMA accumulator

__device__ __forceinline__ unsigned short f2bf(float f) {
    unsigned u = __float_as_uint(f);
    u = (u + 0x7fffu + ((u >> 16) & 1u)) >> 16;   // RNE
    return (unsigned short)u;
}

__device__ __forceinline__ void glds16(const unsigned short* g, unsigned short* l) {
    // async global->LDS, 16 B/lane; LDS dest = wave-uniform base + lane*16
    __builtin_amdgcn_global_load_lds(
        (const __attribute__((address_space(1))) void*)g,
        (__attribute__((address_space(3))) void*)l, 16, 0, 0);
}

// ---------------------------------------------------------------------------
// Fused cast kernel. Also zeroes the 2 KB OOB-row scratch (zb).
// ---------------------------------------------------------------------------
__global__ __launch_bounds__(256) void cast_all(
    const float* __restrict__ x,
    const float* __restrict__ Wq, const float* __restrict__ Wk,
    const float* __restrict__ Wv, const float* __restrict__ Wo,
    const float* __restrict__ bq, const float* __restrict__ bk,
    const float* __restrict__ bv,
    unsigned short* __restrict__ xb,
    unsigned short* __restrict__ wqkv, unsigned short* __restrict__ wob,
    float* __restrict__ bqkv, unsigned short* __restrict__ zb)
{
    if (blockIdx.x < 2048) {
        int i = blockIdx.x * 256 + threadIdx.x;
        float4 f = ((const float4*)x)[i];
        ushort4 o;
        o.x = f2bf(f.x); o.y = f2bf(f.y); o.z = f2bf(f.z); o.w = f2bf(f.w);
        ((ushort4*)xb)[i] = o;
    } else if (blockIdx.x < 3072) {
        int gid = (blockIdx.x - 2048) * 256 + threadIdx.x;
        int m   = gid >> 16;
        int idx = gid & 0xFFFF;
        const float* src = (m == 0) ? Wq : (m == 1) ? Wk : (m == 2) ? Wv : Wo;
        float4 f = ((const float4*)src)[idx];
        ushort4 o;
        o.x = f2bf(f.x); o.y = f2bf(f.y); o.z = f2bf(f.z); o.w = f2bf(f.w);
        if (m < 3) ((ushort4*)wqkv)[(m << 16) + idx] = o;
        else       ((ushort4*)wob)[idx] = o;
    } else {
        for (int i = threadIdx.x; i < 384; i += 256) {
            const float* src = (i < 128) ? bq : (i < 256) ? bk : bv;
            ((float4*)bqkv)[i] = ((const float4*)src)[i & 127];
        }
        // zero 2 KB OOB scratch
        if (threadIdx.x < 128) {
            float4 z; z.x = 0.f; z.y = 0.f; z.z = 0.f; z.w = 0.f;
            ((float4*)zb)[threadIdx.x] = z;
        }
    }
}

// ---------------------------------------------------------------------------
// FUSED QKV-projection + local-window attention (round-2 best, reverted).
// W stays LDS-staged via glds16: the staging is the COALESCING device —
// glds16 fetches contiguous 1KB wave-lines; ds_read re-gathers into MFMA
// fragment layout at LDS latency. (Round-3's direct global->VGPR fragment
// gather was a 16-row x 1KB-stride scatter -> latency-bound, 3x slower.)
// One block per (64-query tile, head). In-block GEMM computes
//   Q[64x64] = x[q0..q0+64)   @ Wq[hcols]^T   (wave 0)
//   K[96x64] = x[q0-16..+80)  @ Wk[hcols]^T   (waves 1,3)
//   V[96x64] = x[q0-16..+80)  @ Wv[hcols]^T   (waves 2,3)
// straight into the attention LDS tiles, then the band-restricted attention.
// LDS: staging S 36 KB (overlaid with Pws) + Qs/Ks/Vs 37.6 KB = 73.6 KB
// -> 2 blocks/CU; grid 512 = exactly 2/CU.
// ---------------------------------------------------------------------------
#define QLD 72
#define VLD 76

__global__ __launch_bounds__(256) void qkv_attn(
    const unsigned short* __restrict__ xb,
    const unsigned short* __restrict__ wqkv,
    const float* __restrict__ bqkv,
    const unsigned short* __restrict__ zb,
    unsigned short* __restrict__ att)
{
    // S rows: [0..95] = x rows (q0-16 .. q0+79), [96..159]=Wq, [160..223]=Wk,
    // [224..287]=Wv (rows = output cols h*64..h*64+63). 64 bf16 per row (BK).
    __shared__ unsigned short S[288 * 64];        // 36 KB, reused as Pws later
    __shared__ unsigned short Qs[64][QLD];
    __shared__ unsigned short Ks[96][QLD];
    __shared__ unsigned short Vs[96][VLD];

    const int q0 = blockIdx.x * 64;
    const int bh = blockIdx.y;
    const int b = bh >> 3, h = bh & 7;
    const int t = threadIdx.x;
    const int w = t >> 6, l = t & 63;
    const int quad = l >> 4, lo = l & 15;
    const int lr  = l >> 3;
    const int csw = ((l & 7) ^ lr) * 8;      // swizzled source col offset

    // ---- staging pointers: 9 chunks/wave, 8 rows x 64 cols each ----
    const unsigned short* src[9];
    unsigned short* dst[9];
    #pragma unroll
    for (int i = 0; i < 9; ++i) {
        int c = w * 9 + i;
        dst[i] = &S[c * 512];
        if (c < 12) {                          // x rows 8c..8c+7 (g = q0-16+8c+lr)
            int g0 = q0 - 16 + 8 * c;          // chunks are fully in or fully out
            src[i] = (g0 >= 0 && g0 < T_)
                   ? (xb + (size_t)(b * T_ + g0 + lr) * 512 + csw)
                   : (zb + csw);               // zeros; +k0<=448 stays in 2 KB
        } else {                               // W region
            int wr0 = (c - 12) * 8;            // 0..191
            int m = wr0 >> 6;                  // 0=q,1=k,2=v
            int r = (wr0 & 63) + lr;           // output col within head
            src[i] = wqkv + (size_t)m * 262144 + (size_t)(h * 64 + r) * 512 + csw;
        }
    }

    floatx4 acc[4][4];
    #pragma unroll
    for (int m = 0; m < 4; ++m)
        #pragma unroll
        for (int n = 0; n < 4; ++n) acc[m][n] = (floatx4)0.0f;

    const int swlo = lo & 7;

    // ---- in-block GEMM: K=512, BK=64 ----
    for (int k0 = 0; k0 < 512; k0 += 64) {
        #pragma unroll
        for (int i = 0; i < 9; ++i) glds16(src[i] + k0, dst[i]);
        __syncthreads();

        #pragma unroll
        for (int ks = 0; ks < 2; ++ks) {
            const int cg = ((ks * 4 + quad) ^ swlo) * 8;
            if (w != 3) {
                // wave0: Q (x rows 16..79); wave1: K rows 0..63; wave2: V rows 0..63
                const int ab = (w == 0) ? 16 : 0;
                const int bb = 96 + (w << 6);
                short8 a[4], bf[4];
                #pragma unroll
                for (int m = 0; m < 4; ++m)
                    a[m] = *(const short8*)(&S[(ab + m * 16 + lo) * 64 + cg]);
                #pragma unroll
                for (int n = 0; n < 4; ++n)
                    bf[n] = *(const short8*)(&S[(bb + n * 16 + lo) * 64 + cg]);
                #pragma unroll
                for (int m = 0; m < 4; ++m)
                    #pragma unroll
                    for (int n = 0; n < 4; ++n)
                        acc[m][n] = __builtin_amdgcn_mfma_f32_16x16x32_bf16(a[m], bf[n], acc[m][n], 0, 0, 0);
            } else {
                // wave3: K rows 64..95 (acc[0..1]) + V rows 64..95 (acc[2..3])
                short8 a2[2], bk4[4], bv4[4];
                #pragma unroll
                for (int j = 0; j < 2; ++j)
                    a2[j] = *(const short8*)(&S[(64 + j * 16 + lo) * 64 + cg]);
                #pragma unroll
                for (int n = 0; n < 4; ++n) {
                    bk4[n] = *(const short8*)(&S[(160 + n * 16 + lo) * 64 + cg]);
                    bv4[n] = *(const short8*)(&S[(224 + n * 16 + lo) * 64 + cg]);
                }
                #pragma unroll
                for (int n = 0; n < 4; ++n) {
                    acc[0][n] = __builtin_amdgcn_mfma_f32_16x16x32_bf16(a2[0], bk4[n], acc[0][n], 0, 0, 0);
                    acc[1][n] = __builtin_amdgcn_mfma_f32_16x16x32_bf16(a2[1], bk4[n], acc[1][n], 0, 0, 0);
                    acc[2][n] = __builtin_amdgcn_mfma_f32_16x16x32_bf16(a2[0], bv4[n], acc[2][n], 0, 0, 0);
                    acc[3][n] = __builtin_amdgcn_mfma_f32_16x16x32_bf16(a2[1], bv4[n], acc[3][n], 0, 0, 0);
                }
            }
        }
        __syncthreads();
    }

    // ---- epilogue: Q/K/V -> attn LDS tiles, bias + f2bf ----
    if (w == 0) {
        #pragma unroll
        for (int n = 0; n < 4; ++n) {
            float bb = bqkv[h * 64 + n * 16 + lo];
            #pragma unroll
            for (int m = 0; m < 4; ++m)
                #pragma unroll
                for (int r = 0; r < 4; ++r)
                    Qs[m * 16 + quad * 4 + r][n * 16 + lo] = f2bf(acc[m][n][r] + bb);
        }
    } else if (w == 1) {
        #pragma unroll
        for (int n = 0; n < 4; ++n) {
            float bb = bqkv[512 + h * 64 + n * 16 + lo];
            #pragma unroll
            for (int m = 0; m < 4; ++m)
                #pragma unroll
                for (int r = 0; r < 4; ++r)
                    Ks[m * 16 + quad * 4 + r][n * 16 + lo] = f2bf(acc[m][n][r] + bb);
        }
    } else if (w == 2) {
        #pragma unroll
        for (int n = 0; n < 4; ++n) {
            float bb = bqkv[1024 + h * 64 + n * 16 + lo];
            #pragma unroll
            for (int m = 0; m < 4; ++m)
                #pragma unroll
                for (int r = 0; r < 4; ++r)
                    Vs[m * 16 + quad * 4 + r][n * 16 + lo] = f2bf(acc[m][n][r] + bb);
        }
    } else {
        #pragma unroll
        for (int n = 0; n < 4; ++n) {
            float bbk = bqkv[512  + h * 64 + n * 16 + lo];
            float bbv = bqkv[1024 + h * 64 + n * 16 + lo];
            #pragma unroll
            for (int j = 0; j < 2; ++j)
                #pragma unroll
                for (int r = 0; r < 4; ++r) {
                    Ks[64 + j * 16 + quad * 4 + r][n * 16 + lo] = f2bf(acc[j][n][r] + bbk);
                    Vs[64 + j * 16 + quad * 4 + r][n * 16 + lo] = f2bf(acc[2 + j][n][r] + bbv);
                }
        }
    }
    __syncthreads();

    // ---- attention phase (proven band-restricted structure) ----
    unsigned short (*Pws)[16][QLD] = (unsigned short (*)[16][QLD])S;  // overlay

    const int wq  = w;
    const int ks0 = wq >> 1;                      // first 32-key chunk
    const int kb  = ks0 * 2;                      // first 16-key tile

    // S = Q K^T over 4 key tiles
    floatx4 Sf[4];
    #pragma unroll
    for (int tt = 0; tt < 4; ++tt) Sf[tt] = (floatx4)0.0f;
    short8 aq[2];
    #pragma unroll
    for (int ks = 0; ks < 2; ++ks)
        aq[ks] = *(const short8*)(&Qs[wq * 16 + lo][ks * 32 + quad * 8]);
    #pragma unroll
    for (int tt = 0; tt < 4; ++tt) {
        #pragma unroll
        for (int ks = 0; ks < 2; ++ks) {
            short8 bk8 = *(const short8*)(&Ks[(kb + tt) * 16 + lo][ks * 32 + quad * 8]);
            Sf[tt] = __builtin_amdgcn_mfma_f32_16x16x32_bf16(aq[ks], bk8, Sf[tt], 0, 0, 0);
        }
    }

    // masked softmax
    float inv_r[4];
    #pragma unroll
    for (int r = 0; r < 4; ++r) {
        int qi = q0 + wq * 16 + quad * 4 + r;
        float mx = -1e30f;
        float sv[4]; bool vd[4];
        #pragma unroll
        for (int tt = 0; tt < 4; ++tt) {
            int j = q0 - WHALF_ + (kb + tt) * 16 + lo;
            bool ok = (j >= qi - WHALF_) && (j < qi + WHALF_) && (j >= 0) && (j < T_);
            float s = Sf[tt][r] * 0.125f;
            sv[tt] = s; vd[tt] = ok;
            mx = (ok && s > mx) ? s : mx;
        }
        #pragma unroll
        for (int mm = 1; mm < 16; mm <<= 1) mx = fmaxf(mx, __shfl_xor(mx, mm, 16));
        float den = 0.f;
        #pragma unroll
        for (int tt = 0; tt < 4; ++tt) {
            float e = vd[tt] ? __expf(sv[tt] - mx) : 0.f;
            Pws[wq][quad * 4 + r][tt * 16 + lo] = f2bf(e);
            den += e;
        }
        #pragma unroll
        for (int mm = 1; mm < 16; mm <<= 1) den += __shfl_xor(den, mm, 16);
        inv_r[r] = 1.0f / den;
    }
    // Pws is wave-private: in-wave lgkmcnt ordering suffices, no barrier.

    // O = P V over 2 key chunks; B-frags gathered from row-major Vs
    floatx4 O[4];
    #pragma unroll
    for (int nt = 0; nt < 4; ++nt) O[nt] = (floatx4)0.0f;
    #pragma unroll
    for (int ksr = 0; ksr < 2; ++ksr) {
        short8 ap = *(const short8*)(&Pws[wq][lo][ksr * 32 + quad * 8]);
        const int krow = (ks0 + ksr) * 32 + quad * 8;
        #pragma unroll
        for (int nt = 0; nt < 4; ++nt) {
            short8 bv8;
            #pragma unroll
            for (int j = 0; j < 8; ++j)
                bv8[j] = (short)Vs[krow + j][nt * 16 + lo];
            O[nt] = __builtin_amdgcn_mfma_f32_16x16x32_bf16(ap, bv8, O[nt], 0, 0, 0);
        }
    }

    // epilogue: scale by 1/den, bf16 out
    #pragma unroll
    for (int r = 0; r < 4; ++r) {
        int qi = q0 + wq * 16 + quad * 4 + r;
        size_t rowb = (size_t)(b * T_ + qi) * D_ + h * HD_;
        #pragma unroll
        for (int nt = 0; nt < 4; ++nt)
            att[rowb + nt * 16 + lo] = f2bf(O[nt][r] * inv_r[r]);
    }
}

// ---------------------------------------------------------------------------
// GEMM2 (round-2 best, reverted): out[4096,512](f32) = attb(bf16) @ wob^T + bo.
// 64x64 tile, LDS-staged (coalesced glds16), 512 blocks = 2/CU; 2x2 wave
// split: per K-step 4 ds_read_b128 for 4 MFMA.
// ---------------------------------------------------------------------------
__global__ __launch_bounds__(256) void gemm_out(
    const unsigned short* __restrict__ attb, const unsigned short* __restrict__ wob,
    const float* __restrict__ bo, float* __restrict__ out)
{
    __shared__ unsigned short As[64 * 64];
    __shared__ unsigned short Bs[64 * 64];

    const int t  = threadIdx.x;
    const int m0 = blockIdx.x * 64;
    const int n0 = blockIdx.y * 64;
    const int w  = t >> 6, l = t & 63;
    const int quad = l >> 4, lo = l & 15;

    const int lr = l >> 3;
    const int csw = ((l & 7) ^ lr) * 8;
    const unsigned short* Ag[2]; unsigned short* ldsA[2];
    const unsigned short* Bg[2]; unsigned short* ldsB[2];
    #pragma unroll
    for (int p = 0; p < 2; ++p) {
        Ag[p] = attb + (size_t)(m0 + 16 * w + 8 * p + lr) * 512 + csw;
        ldsA[p] = &As[(16 * w + 8 * p) * 64];
        Bg[p] = wob + (size_t)(n0 + 16 * w + 8 * p + lr) * 512 + csw;
        ldsB[p] = &Bs[(16 * w + 8 * p) * 64];
    }

    floatx4 acc[2][2];
    #pragma unroll
    for (int m = 0; m < 2; ++m)
        #pragma unroll
        for (int n = 0; n < 2; ++n) acc[m][n] = (floatx4)0.0f;

    const int wr = w >> 1, wc = w & 1;
    const int swlo = lo & 7;

    for (int k0 = 0; k0 < 512; k0 += 64) {
        #pragma unroll
        for (int p = 0; p < 2; ++p) { glds16(Ag[p] + k0, ldsA[p]); glds16(Bg[p] + k0, ldsB[p]); }
        __syncthreads();

        #pragma unroll
        for (int ks = 0; ks < 2; ++ks) {
            const int cg = ((ks * 4 + quad) ^ swlo) * 8;
            short8 a[2], bf[2];
            #pragma unroll
            for (int m = 0; m < 2; ++m)
                a[m] = *(const short8*)(&As[(wr * 32 + m * 16 + lo) * 64 + cg]);
            #pragma unroll
            for (int n = 0; n < 2; ++n)
                bf[n] = *(const short8*)(&Bs[(wc * 32 + n * 16 + lo) * 64 + cg]);
            #pragma unroll
            for (int m = 0; m < 2; ++m)
                #pragma unroll
                for (int n = 0; n < 2; ++n)
                    acc[m][n] = __builtin_amdgcn_mfma_f32_16x16x32_bf16(a[m], bf[n], acc[m][n], 0, 0, 0);
        }
        __syncthreads();
    }

    #pragma unroll
    for (int n = 0; n < 2; ++n) {
        int col = n0 + wc * 32 + n * 16 + lo;
        float bv = bo[col];
        #pragma unroll
        for (int m = 0; m < 2; ++m) {
            #pragma unroll
            for (int r = 0; r < 4; ++r) {
                int row = m0 + wr * 32 + m * 16 + quad * 4 + r;
                out[(size_t)row * 512 + col] = acc[m][n][r] + bv;
            }
        }
    }
}

// ---------------------------------------------------------------------------
extern "C" void kernel_launch(void* const* d_in, const int* in_sizes, int n_in,
                              void* d_out, int out_size, void* d_ws, size_t ws_size,
                              hipStream_t stream) {
    const float* x  = (const float*)d_in[0];
    const float* Wq = (const float*)d_in[1];
    const float* bq = (const float*)d_in[2];
    const float* Wk = (const float*)d_in[3];
    const float* bk = (const float*)d_in[4];
    const float* Wv = (const float*)d_in[5];
    const float* bv = (const float*)d_in[6];
    const float* Wo = (const float*)d_in[7];
    const float* bo = (const float*)d_in[8];
    float* out = (float*)d_out;

    char* ws = (char*)d_ws;
    unsigned short* xb   = (unsigned short*)(ws);                 //  4.00 MB
    unsigned short* wqkv = (unsigned short*)(ws +  4194304);      //  1.50 MB
    unsigned short* wob  = (unsigned short*)(ws +  5767168);      //  0.50 MB
    float*          bqkv = (float*)         (ws +  6291456);      //  6 KB
    unsigned short* zb   = (unsigned short*)(ws +  6297600);      //  2 KB zeros
    unsigned short* attb = (unsigned short*)(ws +  6299648);      //  4.00 MB

    cast_all<<<3073, 256, 0, stream>>>(x, Wq, Wk, Wv, Wo, bq, bk, bv,
                                       xb, wqkv, wob, bqkv, zb);

    // fused QKV projection + local attention: 512 blocks = 2/CU
    qkv_attn<<<dim3(T_ / 64, B_ * H_), 256, 0, stream>>>(
        xb, wqkv, bqkv, zb, attb);

    // output projection: 64x64 tiles, 512 blocks = 2/CU
    gemm_out<<<dim3(Mtot / 64, D_ / 64), 256, 0, stream>>>(attb, wob, bo, out);
}